// Round 1
// baseline (246.260 us; speedup 1.0000x reference)
//
#include <hip/hip_runtime.h>

#define H_IMG 128
#define W_IMG 128
#define NQ (H_IMG * W_IMG)
#define CIN 256
#define NH 8
#define NP 4
#define DH 32

typedef __bf16 bf16x8 __attribute__((ext_vector_type(8)));
typedef float f32x4 __attribute__((ext_vector_type(4)));

// ---------------- weight prep: transpose to BT[N][K] and cast to bf16 ----------------
__global__ __launch_bounds__(256) void prep_weights(
    const float* __restrict__ Wval, const float* __restrict__ Wout,
    const float* __restrict__ Woff, const float* __restrict__ Wattn,
    const float* __restrict__ boff, const float* __restrict__ battn,
    __bf16* __restrict__ btv, __bf16* __restrict__ bto,
    __bf16* __restrict__ btoa, float* __restrict__ bias96) {
  int id = blockIdx.x * 256 + threadIdx.x;
  if (id < 256 * 256) {
    int n = id >> 8, k = id & 255;
    btv[n * 256 + k] = (__bf16)Wval[k * 256 + n];
    bto[n * 256 + k] = (__bf16)Wout[k * 256 + n];
  }
  if (id < 96 * 256) {
    int n = id >> 8, k = id & 255;
    float w = (n < 64) ? Woff[k * 64 + n] : Wattn[k * 32 + (n - 64)];
    btoa[n * 256 + k] = (__bf16)w;
  }
  if (id < 96) {
    bias96[id] = (id < 64) ? boff[id] : battn[id - 64];
  }
}

// ---------------- bf16 MFMA GEMM: C[M x N] = A[M x K] * BT^T + bias (+ addm) --------
// A fp32 row-major, BT bf16 [N x K] row-major. One wave per 16-row strip.
// mfma_f32_16x16x32_bf16 layouts (HW-verified):
//   A frag: lane holds A[m = lane&15][k = (lane>>4)*8 + j], j=0..7
//   B frag: lane holds B[k = (lane>>4)*8 + j][n = lane&15]  (== BT[n][k])
//   C/D:    col = lane&15, row = (lane>>4)*4 + reg
template <int NT, bool ADD>
__global__ __launch_bounds__(256) void gemm_mfma(
    const float* __restrict__ A, const __bf16* __restrict__ BT,
    const float* __restrict__ bias, const float* __restrict__ addm,
    float* __restrict__ C, int K) {
  const int lane = threadIdx.x & 63;
  const int wave = threadIdx.x >> 6;
  const int m0 = (blockIdx.x * 4 + wave) * 16;
  const int r = lane & 15;
  const int q = lane >> 4;
  f32x4 zero = {0.f, 0.f, 0.f, 0.f};
  f32x4 acc[NT];
#pragma unroll
  for (int i = 0; i < NT; ++i) acc[i] = zero;
  const float* Arow = A + (size_t)(m0 + r) * K + q * 8;
  for (int k0 = 0; k0 < K; k0 += 32) {
    float4 af0 = *(const float4*)(Arow + k0);
    float4 af1 = *(const float4*)(Arow + k0 + 4);
    bf16x8 a;
    a[0] = (__bf16)af0.x; a[1] = (__bf16)af0.y;
    a[2] = (__bf16)af0.z; a[3] = (__bf16)af0.w;
    a[4] = (__bf16)af1.x; a[5] = (__bf16)af1.y;
    a[6] = (__bf16)af1.z; a[7] = (__bf16)af1.w;
#pragma unroll
    for (int nt = 0; nt < NT; ++nt) {
      bf16x8 b = *(const bf16x8*)(BT + (size_t)(nt * 16 + r) * K + k0 + q * 8);
      acc[nt] = __builtin_amdgcn_mfma_f32_16x16x32_bf16(a, b, acc[nt], 0, 0, 0);
    }
  }
  const int N = NT * 16;
#pragma unroll
  for (int nt = 0; nt < NT; ++nt) {
#pragma unroll
    for (int rr = 0; rr < 4; ++rr) {
      int row = m0 + q * 4 + rr;
      int col = nt * 16 + r;
      float val = acc[nt][rr] + bias[col];
      if (ADD) val += addm[(size_t)row * N + col];
      C[(size_t)row * N + col] = val;
    }
  }
}

// ---------------- sampling: softmax over P + bilinear gather-weighted sum -----------
// One wave per query; lane -> (head = lane>>3, d4 = (lane&7)*4). float4 gathers.
__global__ __launch_bounds__(256) void sample_kernel(
    const float* __restrict__ v, const float* __restrict__ oa,
    float* __restrict__ attn) {
  const int lane = threadIdx.x & 63;
  const int wave = threadIdx.x >> 6;
  const int d4 = (lane & 7) * 4;
  const int head = lane >> 3;
  const int QPB = 8;
  int base_row = (blockIdx.x * 4 + wave) * QPB;
  for (int it = 0; it < QPB; ++it) {
    int row = base_row + it;
    int b = row >> 14;       // nq = 16384
    int qi = row & (NQ - 1);
    int x = qi & (W_IMG - 1);
    int y = qi >> 7;
    const float* oarow = oa + (size_t)row * 96;
    // softmax over the 4 points of this head (redundant across the 8 d-lanes)
    float l0 = oarow[64 + head * 4 + 0];
    float l1 = oarow[64 + head * 4 + 1];
    float l2 = oarow[64 + head * 4 + 2];
    float l3 = oarow[64 + head * 4 + 3];
    float mx = fmaxf(fmaxf(l0, l1), fmaxf(l2, l3));
    float e0 = __expf(l0 - mx), e1 = __expf(l1 - mx);
    float e2 = __expf(l2 - mx), e3 = __expf(l3 - mx);
    float inv = 1.f / (e0 + e1 + e2 + e3);
    float awp[4] = {e0 * inv, e1 * inv, e2 * inv, e3 * inv};
    float accx = 0.f, accy = 0.f, accz = 0.f, accw = 0.f;
    const float* vb = v + (size_t)b * NQ * 256 + head * DH + d4;
#pragma unroll
    for (int p = 0; p < NP; ++p) {
      float ox = oarow[head * 8 + p * 2 + 0];
      float oy = oarow[head * 8 + p * 2 + 1];
      float ix = (float)x + ox;
      float iy = (float)y + oy;
      float x0f = floorf(ix), y0f = floorf(iy);
      float wx1 = ix - x0f, wy1 = iy - y0f;
      int x0 = (int)x0f, y0 = (int)y0f;
      float wgt[4] = {(1.f - wx1) * (1.f - wy1), wx1 * (1.f - wy1),
                      (1.f - wx1) * wy1, wx1 * wy1};
      int xs[4] = {x0, x0 + 1, x0, x0 + 1};
      int ysv[4] = {y0, y0, y0 + 1, y0 + 1};
#pragma unroll
      for (int c = 0; c < 4; ++c) {
        int xi = xs[c], yi = ysv[c];
        bool valid = (xi >= 0) & (xi < W_IMG) & (yi >= 0) & (yi < H_IMG);
        int xc = xi < 0 ? 0 : (xi > W_IMG - 1 ? W_IMG - 1 : xi);
        int yc = yi < 0 ? 0 : (yi > H_IMG - 1 ? H_IMG - 1 : yi);
        float wv = awp[p] * wgt[c] * (valid ? 1.f : 0.f);
        const float4 g = *(const float4*)(vb + (size_t)(yc * W_IMG + xc) * 256);
        accx += wv * g.x;
        accy += wv * g.y;
        accz += wv * g.z;
        accw += wv * g.w;
      }
    }
    float4* dst = (float4*)(attn + (size_t)row * 256 + head * DH + d4);
    *dst = make_float4(accx, accy, accz, accw);
  }
}

extern "C" void kernel_launch(void* const* d_in, const int* in_sizes, int n_in,
                              void* d_out, int out_size, void* d_ws, size_t ws_size,
                              hipStream_t stream) {
  const float* query  = (const float*)d_in[0];
  const float* value  = (const float*)d_in[1];
  const float* W_off  = (const float*)d_in[2];
  const float* b_off  = (const float*)d_in[3];
  const float* W_attn = (const float*)d_in[4];
  const float* b_attn = (const float*)d_in[5];
  const float* W_val  = (const float*)d_in[6];
  const float* b_val  = (const float*)d_in[7];
  const float* W_out  = (const float*)d_in[8];
  const float* b_out  = (const float*)d_in[9];
  float* out = (float*)d_out;

  char* ws = (char*)d_ws;
  __bf16* btv    = (__bf16*)(ws + 0);          // 128 KB
  __bf16* bto    = (__bf16*)(ws + 131072);     // 128 KB
  __bf16* btoa   = (__bf16*)(ws + 262144);     // 48 KB
  float*  bias96 = (float*)(ws + 311296);      // 384 B
  float*  v      = (float*)(ws + 524288);      // 32 MB
  float*  oa     = (float*)(ws + 34078720);    // 12 MB
  float*  attn   = (float*)(ws + 46661632);    // 32 MB

  const int M = in_sizes[0] / CIN;  // 32768 = bs * nq

  prep_weights<<<256, 256, 0, stream>>>(W_val, W_out, W_off, W_attn,
                                        b_off, b_attn, btv, bto, btoa, bias96);
  gemm_mfma<16, false><<<M / 64, 256, 0, stream>>>(value, btv, b_val, nullptr, v, CIN);
  gemm_mfma<6, false><<<M / 64, 256, 0, stream>>>(query, btoa, bias96, nullptr, oa, CIN);
  sample_kernel<<<M / 32, 256, 0, stream>>>(v, oa, attn);
  gemm_mfma<16, true><<<M / 64, 256, 0, stream>>>(attn, bto, b_out, query, out, CIN);
}

// Round 2
// 201.444 us; speedup vs baseline: 1.2225x; 1.2225x over previous
//
#include <hip/hip_runtime.h>
#include <type_traits>

#define H_IMG 128
#define W_IMG 128
#define NQ (H_IMG * W_IMG)
#define CIN 256
#define NH 8
#define NP 4
#define DH 32

typedef __bf16 bf16x4 __attribute__((ext_vector_type(4)));
typedef __bf16 bf16x8 __attribute__((ext_vector_type(8)));
typedef float f32x4 __attribute__((ext_vector_type(4)));

// ---------------- weight prep: transpose to BT[N][K] and cast to bf16 ----------------
__global__ __launch_bounds__(256) void prep_weights(
    const float* __restrict__ Wval, const float* __restrict__ Wout,
    const float* __restrict__ Woff, const float* __restrict__ Wattn,
    const float* __restrict__ boff, const float* __restrict__ battn,
    __bf16* __restrict__ btv, __bf16* __restrict__ bto,
    __bf16* __restrict__ btoa, float* __restrict__ bias96) {
  int id = blockIdx.x * 256 + threadIdx.x;
  if (id < 256 * 256) {
    int n = id >> 8, k = id & 255;
    btv[n * 256 + k] = (__bf16)Wval[k * 256 + n];
    bto[n * 256 + k] = (__bf16)Wout[k * 256 + n];
  }
  if (id < 96 * 256) {
    int n = id >> 8, k = id & 255;
    float w = (n < 64) ? Woff[k * 64 + n] : Wattn[k * 32 + (n - 64)];
    btoa[n * 256 + k] = (__bf16)w;
  }
  if (id < 96) {
    bias96[id] = (id < 64) ? boff[id] : battn[id - 64];
  }
}

// ---------------- tiled bf16 MFMA GEMM --------------------------------------------
// C[M x N] = A[M x 256] * BT^T + bias (+ addm). BT bf16 [N x 256] row-major.
// Block = 256 threads (4 waves). Tile: BM=64 rows x BN=NTW*32 cols.
//   wave (w&1) -> M half (32 rows, 2 m-tiles), wave (w>>1) -> N half (NTW*16 cols).
// A staged into LDS as bf16 with padded row stride 40 elems (80 B, 16B-aligned,
// conflict-light for both b64/b128 writes and b128 frag reads).
// B frags loaded straight from global (BT is 128KB, L1/L2 resident) — no barrier
// dependency, so they act as a prefetch stream the compiler can hoist.
// mfma_f32_16x16x32_bf16 layouts (HW-verified, carried from passing round-0 kernel):
//   A frag: lane holds A[m = lane&15][k = (lane>>4)*8 + j]
//   B frag: lane holds BT[n = lane&15][k = (lane>>4)*8 + j]
//   C/D:    col = lane&15, row = (lane>>4)*4 + reg
#define AS_STRIDE 40
template <typename TA, typename TC, int NTW, bool ADD>
__global__ __launch_bounds__(256) void gemm_tile(
    const TA* __restrict__ A, const __bf16* __restrict__ BT,
    const float* __restrict__ bias, const float* __restrict__ addm,
    TC* __restrict__ C, int N) {
  const int t = threadIdx.x;
  const int lane = t & 63;
  const int wave = t >> 6;
  const int r = lane & 15;
  const int q = lane >> 4;
  const int gm0 = blockIdx.x * 64;
  const int n0 = blockIdx.y * (NTW * 32) + (wave >> 1) * (NTW * 16);
  const int mw = (wave & 1) * 32;

  __shared__ __bf16 As[64 * AS_STRIDE];

  f32x4 acc[2][NTW];
#pragma unroll
  for (int mt = 0; mt < 2; ++mt)
#pragma unroll
    for (int nt = 0; nt < NTW; ++nt) acc[mt][nt] = (f32x4){0.f, 0.f, 0.f, 0.f};

  for (int kt = 0; kt < 8; ++kt) {
    const int k0 = kt * 32;
    __syncthreads();
    if constexpr (std::is_same<TA, float>::value) {
      // 64x32 fp32 tile: 2 iterations of 256 threads x float4, convert to bf16.
#pragma unroll
      for (int it = 0; it < 2; ++it) {
        int row = it * 32 + (t >> 3);
        int kc = (t & 7) * 4;
        float4 f = *(const float4*)(A + (size_t)(gm0 + row) * 256 + k0 + kc);
        bf16x4 hh;
        hh[0] = (__bf16)f.x; hh[1] = (__bf16)f.y;
        hh[2] = (__bf16)f.z; hh[3] = (__bf16)f.w;
        *(bf16x4*)(&As[row * AS_STRIDE + kc]) = hh;
      }
    } else {
      // 64x32 bf16 tile: 1 iteration of 256 threads x bf16x8.
      int row = t >> 2;
      int kc = (t & 3) * 8;
      bf16x8 hh = *(const bf16x8*)(A + (size_t)(gm0 + row) * 256 + k0 + kc);
      *(bf16x8*)(&As[row * AS_STRIDE + kc]) = hh;
    }
    __syncthreads();
    bf16x8 bfr[NTW];
#pragma unroll
    for (int nt = 0; nt < NTW; ++nt)
      bfr[nt] = *(const bf16x8*)(BT + (size_t)(n0 + nt * 16 + r) * 256 + k0 + q * 8);
#pragma unroll
    for (int mt = 0; mt < 2; ++mt) {
      bf16x8 a = *(const bf16x8*)(&As[(mw + mt * 16 + r) * AS_STRIDE + q * 8]);
#pragma unroll
      for (int nt = 0; nt < NTW; ++nt)
        acc[mt][nt] = __builtin_amdgcn_mfma_f32_16x16x32_bf16(a, bfr[nt], acc[mt][nt], 0, 0, 0);
    }
  }

#pragma unroll
  for (int mt = 0; mt < 2; ++mt)
#pragma unroll
    for (int nt = 0; nt < NTW; ++nt)
#pragma unroll
      for (int rr = 0; rr < 4; ++rr) {
        int row = gm0 + mw + mt * 16 + q * 4 + rr;
        int col = n0 + nt * 16 + r;
        float val = acc[mt][nt][rr] + bias[col];
        if constexpr (ADD) val += addm[(size_t)row * N + col];
        C[(size_t)row * N + col] = (TC)val;
      }
}

// ---------------- sampling: softmax over P + bilinear gather-weighted sum -----------
// v is bf16 [b][q][head*32+d]. Lane map: 64 = 2 queries x 8 heads x 4 d-chunks(8).
// Each lane gathers bf16x8 (16 B) per corner; math in fp32; attn written bf16.
__global__ __launch_bounds__(256) void sample_kernel(
    const __bf16* __restrict__ v, const float* __restrict__ oa,
    __bf16* __restrict__ attn) {
  const int lane = threadIdx.x & 63;
  const int wave = threadIdx.x >> 6;
  const int ql = lane >> 5;          // query within pair
  const int head = (lane >> 2) & 7;  // 0..7
  const int c8 = (lane & 3) * 8;     // d offset (x8 bf16)
  const int QPW = 8;
  int base_row = (blockIdx.x * 4 + wave) * QPW + ql;
  for (int it = 0; it < QPW; it += 2) {
    int row = base_row + it;
    int b = row >> 14;  // nq = 16384
    int qi = row & (NQ - 1);
    int x = qi & (W_IMG - 1);
    int y = qi >> 7;
    const float* oarow = oa + (size_t)row * 96;
    float l0 = oarow[64 + head * 4 + 0];
    float l1 = oarow[64 + head * 4 + 1];
    float l2 = oarow[64 + head * 4 + 2];
    float l3 = oarow[64 + head * 4 + 3];
    float mx = fmaxf(fmaxf(l0, l1), fmaxf(l2, l3));
    float e0 = __expf(l0 - mx), e1 = __expf(l1 - mx);
    float e2 = __expf(l2 - mx), e3 = __expf(l3 - mx);
    float inv = 1.f / (e0 + e1 + e2 + e3);
    float awp[4] = {e0 * inv, e1 * inv, e2 * inv, e3 * inv};
    float acc[8] = {0.f, 0.f, 0.f, 0.f, 0.f, 0.f, 0.f, 0.f};
    const __bf16* vb = v + (size_t)b * NQ * 256 + head * DH + c8;
#pragma unroll
    for (int p = 0; p < NP; ++p) {
      float ox = oarow[head * 8 + p * 2 + 0];
      float oy = oarow[head * 8 + p * 2 + 1];
      float ix = (float)x + ox;
      float iy = (float)y + oy;
      float x0f = floorf(ix), y0f = floorf(iy);
      float wx1 = ix - x0f, wy1 = iy - y0f;
      int x0 = (int)x0f, y0 = (int)y0f;
      float wgt[4] = {(1.f - wx1) * (1.f - wy1), wx1 * (1.f - wy1),
                      (1.f - wx1) * wy1, wx1 * wy1};
      int xs[4] = {x0, x0 + 1, x0, x0 + 1};
      int ysv[4] = {y0, y0, y0 + 1, y0 + 1};
#pragma unroll
      for (int c = 0; c < 4; ++c) {
        int xi = xs[c], yi = ysv[c];
        bool valid = (xi >= 0) & (xi < W_IMG) & (yi >= 0) & (yi < H_IMG);
        int xc = xi < 0 ? 0 : (xi > W_IMG - 1 ? W_IMG - 1 : xi);
        int yc = yi < 0 ? 0 : (yi > H_IMG - 1 ? H_IMG - 1 : yi);
        float wv = awp[p] * wgt[c] * (valid ? 1.f : 0.f);
        bf16x8 g = *(const bf16x8*)(vb + (size_t)(yc * W_IMG + xc) * 256);
#pragma unroll
        for (int j = 0; j < 8; ++j) acc[j] += wv * (float)g[j];
      }
    }
    bf16x8 o;
#pragma unroll
    for (int j = 0; j < 8; ++j) o[j] = (__bf16)acc[j];
    *(bf16x8*)(attn + (size_t)row * 256 + head * DH + c8) = o;
  }
}

extern "C" void kernel_launch(void* const* d_in, const int* in_sizes, int n_in,
                              void* d_out, int out_size, void* d_ws, size_t ws_size,
                              hipStream_t stream) {
  const float* query  = (const float*)d_in[0];
  const float* value  = (const float*)d_in[1];
  const float* W_off  = (const float*)d_in[2];
  const float* b_off  = (const float*)d_in[3];
  const float* W_attn = (const float*)d_in[4];
  const float* b_attn = (const float*)d_in[5];
  const float* W_val  = (const float*)d_in[6];
  const float* b_val  = (const float*)d_in[7];
  const float* W_out  = (const float*)d_in[8];
  const float* b_out  = (const float*)d_in[9];
  float* out = (float*)d_out;

  char* ws = (char*)d_ws;
  __bf16* btv    = (__bf16*)(ws + 0);          // 128 KB
  __bf16* bto    = (__bf16*)(ws + 131072);     // 128 KB
  __bf16* btoa   = (__bf16*)(ws + 262144);     // 48 KB
  float*  bias96 = (float*)(ws + 311296);      // 384 B
  __bf16* v      = (__bf16*)(ws + 524288);     // 16 MB (bf16)
  float*  oa     = (float*)(ws + 17301504);    // 12 MB (fp32)
  __bf16* attn   = (__bf16*)(ws + 29884416);   // 16 MB (bf16)

  const int M = in_sizes[0] / CIN;  // 32768 = bs * nq

  prep_weights<<<256, 256, 0, stream>>>(W_val, W_out, W_off, W_attn,
                                        b_off, b_attn, btv, bto, btoa, bias96);
  // v = value @ W_val + b_val  (bf16 out)
  gemm_tile<float, __bf16, 4, false><<<dim3(M / 64, 2), 256, 0, stream>>>(
      value, btv, b_val, nullptr, v, 256);
  // oa = query @ [W_off|W_attn] + bias96  (fp32 out, N=96)
  gemm_tile<float, float, 3, false><<<dim3(M / 64, 1), 256, 0, stream>>>(
      query, btoa, bias96, nullptr, oa, 96);
  // attn = deformable sampling (bf16 out)
  sample_kernel<<<M / 32, 256, 0, stream>>>(v, oa, attn);
  // out = attn @ W_out + b_out + query  (fp32 out)
  gemm_tile<__bf16, float, 4, true><<<dim3(M / 64, 2), 256, 0, stream>>>(
      attn, bto, b_out, query, out, 256);
}

// Round 3
// 185.905 us; speedup vs baseline: 1.3247x; 1.0836x over previous
//
#include <hip/hip_runtime.h>
#include <type_traits>

#define H_IMG 128
#define W_IMG 128
#define NQ (H_IMG * W_IMG)
#define CIN 256
#define NH 8
#define NP 4
#define DH 32

typedef __bf16 bf16x4 __attribute__((ext_vector_type(4)));
typedef __bf16 bf16x8 __attribute__((ext_vector_type(8)));
typedef float f32x4 __attribute__((ext_vector_type(4)));

// ---------------- weight prep: transpose to BT[N][K] and cast to bf16 ----------------
__global__ __launch_bounds__(256) void prep_weights(
    const float* __restrict__ Wval, const float* __restrict__ Wout,
    const float* __restrict__ Woff, const float* __restrict__ Wattn,
    const float* __restrict__ boff, const float* __restrict__ battn,
    __bf16* __restrict__ btv, __bf16* __restrict__ bto,
    __bf16* __restrict__ btoa, float* __restrict__ bias96) {
  int id = blockIdx.x * 256 + threadIdx.x;
  if (id < 256 * 256) {
    int n = id >> 8, k = id & 255;
    btv[n * 256 + k] = (__bf16)Wval[k * 256 + n];
    bto[n * 256 + k] = (__bf16)Wout[k * 256 + n];
  }
  if (id < 96 * 256) {
    int n = id >> 8, k = id & 255;
    float w = (n < 64) ? Woff[k * 64 + n] : Wattn[k * 32 + (n - 64)];
    btoa[n * 256 + k] = (__bf16)w;
  }
  if (id < 96) {
    bias96[id] = (id < 64) ? boff[id] : battn[id - 64];
  }
}

// ---------------- 128x64 tiled bf16 MFMA GEMM (N fixed = 256) ----------------------
// C[M x 256] = A[M x 256] * BT^T + bias (+ addm). BT bf16 [256 x 256] row-major.
// Block = 256 threads (4 waves). Tile: BM=128 x BN=64. Wave (w&1) -> M half (64 rows,
// 4 m-tiles), wave (w>>1) -> N half (32 cols, 2 n-tiles) => 8 MFMA / 6 ds_read_b128
// per k-step. A and B both staged in LDS, row stride 40 bf16 (80 B): frag-read rows
// alias banks 2-way only (free per m136).
// mfma_f32_16x16x32_bf16 layouts (HW-verified, carried from passing rounds):
//   A frag: lane holds A[m = lane&15][k = (lane>>4)*8 + j]
//   B frag: lane holds BT[n = lane&15][k = (lane>>4)*8 + j]
//   C/D:    col = lane&15, row = (lane>>4)*4 + reg
// PLANAR epilogue scatters C into head-planar v: v[(col>>5) * M + row][col&31].
template <typename TA, typename TC, bool PLANAR, bool ADD>
__global__ __launch_bounds__(256) void gemm128(
    const TA* __restrict__ A, const __bf16* __restrict__ BT,
    const float* __restrict__ bias, const float* __restrict__ addm,
    TC* __restrict__ C, int M) {
  const int t = threadIdx.x;
  const int lane = t & 63;
  const int wave = t >> 6;
  const int r = lane & 15;
  const int q = lane >> 4;
  const int gm0 = blockIdx.x * 128;
  const int gn0 = blockIdx.y * 64;
  const int wm = (wave & 1) * 64;
  const int wn = (wave >> 1) * 32;

  __shared__ __bf16 As[128 * 40];
  __shared__ __bf16 Bs[64 * 40];

  f32x4 acc[4][2];
#pragma unroll
  for (int mt = 0; mt < 4; ++mt)
#pragma unroll
    for (int nt = 0; nt < 2; ++nt) acc[mt][nt] = (f32x4){0.f, 0.f, 0.f, 0.f};

  for (int kt = 0; kt < 8; ++kt) {
    const int k0 = kt * 32;
    __syncthreads();
    // stage A (128 x 32 -> bf16)
    if constexpr (std::is_same<TA, float>::value) {
#pragma unroll
      for (int it = 0; it < 2; ++it) {
        int row = it * 64 + (t >> 2);
        int kc = (t & 3) * 8;
        const float* src = A + (size_t)(gm0 + row) * 256 + k0 + kc;
        float4 f0 = *(const float4*)src;
        float4 f1 = *(const float4*)(src + 4);
        bf16x8 hh;
        hh[0] = (__bf16)f0.x; hh[1] = (__bf16)f0.y;
        hh[2] = (__bf16)f0.z; hh[3] = (__bf16)f0.w;
        hh[4] = (__bf16)f1.x; hh[5] = (__bf16)f1.y;
        hh[6] = (__bf16)f1.z; hh[7] = (__bf16)f1.w;
        *(bf16x8*)(&As[row * 40 + kc]) = hh;
      }
    } else {
#pragma unroll
      for (int it = 0; it < 2; ++it) {
        int row = it * 64 + (t >> 2);
        int kc = (t & 3) * 8;
        *(bf16x8*)(&As[row * 40 + kc]) =
            *(const bf16x8*)(A + (size_t)(gm0 + row) * 256 + k0 + kc);
      }
    }
    // stage B (64 x 32, already bf16)
    {
      int row = t >> 2;
      int kc = (t & 3) * 8;
      *(bf16x8*)(&Bs[row * 40 + kc]) =
          *(const bf16x8*)(BT + (size_t)(gn0 + row) * 256 + k0 + kc);
    }
    __syncthreads();
    bf16x8 bfr[2];
#pragma unroll
    for (int nt = 0; nt < 2; ++nt)
      bfr[nt] = *(const bf16x8*)(&Bs[(wn + nt * 16 + r) * 40 + q * 8]);
#pragma unroll
    for (int mt = 0; mt < 4; ++mt) {
      bf16x8 a = *(const bf16x8*)(&As[(wm + mt * 16 + r) * 40 + q * 8]);
#pragma unroll
      for (int nt = 0; nt < 2; ++nt)
        acc[mt][nt] =
            __builtin_amdgcn_mfma_f32_16x16x32_bf16(a, bfr[nt], acc[mt][nt], 0, 0, 0);
    }
  }

#pragma unroll
  for (int mt = 0; mt < 4; ++mt)
#pragma unroll
    for (int nt = 0; nt < 2; ++nt)
#pragma unroll
      for (int rr = 0; rr < 4; ++rr) {
        int row = gm0 + wm + mt * 16 + q * 4 + rr;
        int col = gn0 + wn + nt * 16 + r;
        float val = acc[mt][nt][rr] + bias[col];
        if constexpr (ADD) val += addm[(size_t)row * 256 + col];
        if constexpr (PLANAR)
          C[((size_t)(col >> 5) * M + row) * 32 + (col & 31)] = (TC)val;
        else
          C[(size_t)row * 256 + col] = (TC)val;
      }
}

// ---------------- small GEMM for offsets/logits (N = 96) ---------------------------
#define AS_STRIDE 40
__global__ __launch_bounds__(256) void gemm_oa(
    const float* __restrict__ A, const __bf16* __restrict__ BT,
    const float* __restrict__ bias, float* __restrict__ C) {
  const int t = threadIdx.x;
  const int lane = t & 63;
  const int wave = t >> 6;
  const int r = lane & 15;
  const int q = lane >> 4;
  const int gm0 = blockIdx.x * 64;
  const int n0 = (wave >> 1) * 48;
  const int mw = (wave & 1) * 32;
  const int NTW = 3;

  __shared__ __bf16 As[64 * AS_STRIDE];

  f32x4 acc[2][3];
#pragma unroll
  for (int mt = 0; mt < 2; ++mt)
#pragma unroll
    for (int nt = 0; nt < NTW; ++nt) acc[mt][nt] = (f32x4){0.f, 0.f, 0.f, 0.f};

  for (int kt = 0; kt < 8; ++kt) {
    const int k0 = kt * 32;
    __syncthreads();
#pragma unroll
    for (int it = 0; it < 2; ++it) {
      int row = it * 32 + (t >> 3);
      int kc = (t & 7) * 4;
      float4 f = *(const float4*)(A + (size_t)(gm0 + row) * 256 + k0 + kc);
      bf16x4 hh;
      hh[0] = (__bf16)f.x; hh[1] = (__bf16)f.y;
      hh[2] = (__bf16)f.z; hh[3] = (__bf16)f.w;
      *(bf16x4*)(&As[row * AS_STRIDE + kc]) = hh;
    }
    __syncthreads();
    bf16x8 bfr[NTW];
#pragma unroll
    for (int nt = 0; nt < NTW; ++nt)
      bfr[nt] = *(const bf16x8*)(BT + (size_t)(n0 + nt * 16 + r) * 256 + k0 + q * 8);
#pragma unroll
    for (int mt = 0; mt < 2; ++mt) {
      bf16x8 a = *(const bf16x8*)(&As[(mw + mt * 16 + r) * AS_STRIDE + q * 8]);
#pragma unroll
      for (int nt = 0; nt < NTW; ++nt)
        acc[mt][nt] =
            __builtin_amdgcn_mfma_f32_16x16x32_bf16(a, bfr[nt], acc[mt][nt], 0, 0, 0);
    }
  }

#pragma unroll
  for (int mt = 0; mt < 2; ++mt)
#pragma unroll
    for (int nt = 0; nt < NTW; ++nt)
#pragma unroll
      for (int rr = 0; rr < 4; ++rr) {
        int row = gm0 + mw + mt * 16 + q * 4 + rr;
        int col = n0 + nt * 16 + r;
        C[(size_t)row * 96 + col] = acc[mt][nt][rr] + bias[col];
      }
}

// ---------------- sampling: softmax over P + bilinear gather-weighted sum -----------
// v is head-planar bf16: v[head][b][y][x][32]. Lane map: 2 queries x 8 heads x
// 4 d-chunks(8). Each (q,head) tap reads a 64 B pixel record via 4 lanes; the two
// x-corners of a bilinear tap are adjacent records (same/adjacent 128 B line).
__global__ __launch_bounds__(256) void sample_kernel(
    const __bf16* __restrict__ v, const float* __restrict__ oa,
    __bf16* __restrict__ attn, int M) {
  const int lane = threadIdx.x & 63;
  const int wave = threadIdx.x >> 6;
  const int ql = lane >> 5;          // query within pair
  const int head = (lane >> 2) & 7;  // 0..7
  const int c8 = (lane & 3) * 8;     // d offset (x8 bf16)
  const int QPW = 8;
  int base_row = (blockIdx.x * 4 + wave) * QPW + ql;
  const __bf16* vh = v + (size_t)head * M * 32 + c8;
  for (int it = 0; it < QPW; it += 2) {
    int row = base_row + it;
    int b = row >> 14;  // nq = 16384
    int qi = row & (NQ - 1);
    int x = qi & (W_IMG - 1);
    int y = qi >> 7;
    const float* oarow = oa + (size_t)row * 96;
    float l0 = oarow[64 + head * 4 + 0];
    float l1 = oarow[64 + head * 4 + 1];
    float l2 = oarow[64 + head * 4 + 2];
    float l3 = oarow[64 + head * 4 + 3];
    float mx = fmaxf(fmaxf(l0, l1), fmaxf(l2, l3));
    float e0 = __expf(l0 - mx), e1 = __expf(l1 - mx);
    float e2 = __expf(l2 - mx), e3 = __expf(l3 - mx);
    float inv = 1.f / (e0 + e1 + e2 + e3);
    float awp[4] = {e0 * inv, e1 * inv, e2 * inv, e3 * inv};
    float acc[8] = {0.f, 0.f, 0.f, 0.f, 0.f, 0.f, 0.f, 0.f};
    const __bf16* vb = vh + (size_t)b * NQ * 32;
#pragma unroll
    for (int p = 0; p < NP; ++p) {
      float ox = oarow[head * 8 + p * 2 + 0];
      float oy = oarow[head * 8 + p * 2 + 1];
      float ix = (float)x + ox;
      float iy = (float)y + oy;
      float x0f = floorf(ix), y0f = floorf(iy);
      float wx1 = ix - x0f, wy1 = iy - y0f;
      int x0 = (int)x0f, y0 = (int)y0f;
      float wgt[4] = {(1.f - wx1) * (1.f - wy1), wx1 * (1.f - wy1),
                      (1.f - wx1) * wy1, wx1 * wy1};
      int xs[4] = {x0, x0 + 1, x0, x0 + 1};
      int ysv[4] = {y0, y0, y0 + 1, y0 + 1};
#pragma unroll
      for (int c = 0; c < 4; ++c) {
        int xi = xs[c], yi = ysv[c];
        bool valid = (xi >= 0) & (xi < W_IMG) & (yi >= 0) & (yi < H_IMG);
        int xc = xi < 0 ? 0 : (xi > W_IMG - 1 ? W_IMG - 1 : xi);
        int yc = yi < 0 ? 0 : (yi > H_IMG - 1 ? H_IMG - 1 : yi);
        float wv = awp[p] * wgt[c] * (valid ? 1.f : 0.f);
        bf16x8 g = *(const bf16x8*)(vb + (size_t)(yc * W_IMG + xc) * 32);
#pragma unroll
        for (int j = 0; j < 8; ++j) acc[j] += wv * (float)g[j];
      }
    }
    bf16x8 o;
#pragma unroll
    for (int j = 0; j < 8; ++j) o[j] = (__bf16)acc[j];
    *(bf16x8*)(attn + (size_t)row * 256 + head * DH + c8) = o;
  }
}

extern "C" void kernel_launch(void* const* d_in, const int* in_sizes, int n_in,
                              void* d_out, int out_size, void* d_ws, size_t ws_size,
                              hipStream_t stream) {
  const float* query  = (const float*)d_in[0];
  const float* value  = (const float*)d_in[1];
  const float* W_off  = (const float*)d_in[2];
  const float* b_off  = (const float*)d_in[3];
  const float* W_attn = (const float*)d_in[4];
  const float* b_attn = (const float*)d_in[5];
  const float* W_val  = (const float*)d_in[6];
  const float* b_val  = (const float*)d_in[7];
  const float* W_out  = (const float*)d_in[8];
  const float* b_out  = (const float*)d_in[9];
  float* out = (float*)d_out;

  char* ws = (char*)d_ws;
  __bf16* btv    = (__bf16*)(ws + 0);          // 128 KB
  __bf16* bto    = (__bf16*)(ws + 131072);     // 128 KB
  __bf16* btoa   = (__bf16*)(ws + 262144);     // 48 KB
  float*  bias96 = (float*)(ws + 311296);      // 384 B
  __bf16* v      = (__bf16*)(ws + 524288);     // 16 MB (bf16, head-planar)
  float*  oa     = (float*)(ws + 17301504);    // 12 MB (fp32)
  __bf16* attn   = (__bf16*)(ws + 29884416);   // 16 MB (bf16)

  const int M = in_sizes[0] / CIN;  // 32768 = bs * nq

  prep_weights<<<256, 256, 0, stream>>>(W_val, W_out, W_off, W_attn,
                                        b_off, b_attn, btv, bto, btoa, bias96);
  // v = value @ W_val + b_val  (bf16, head-planar)
  gemm128<float, __bf16, true, false><<<dim3(M / 128, 4), 256, 0, stream>>>(
      value, btv, b_val, nullptr, v, M);
  // oa = query @ [W_off|W_attn] + bias96  (fp32, N=96)
  gemm_oa<<<M / 64, 256, 0, stream>>>(query, btoa, bias96, oa);
  // attn = deformable sampling (bf16)
  sample_kernel<<<M / 32, 256, 0, stream>>>(v, oa, attn, M);
  // out = attn @ W_out + b_out + query  (fp32)
  gemm128<__bf16, float, false, true><<<dim3(M / 128, 4), 256, 0, stream>>>(
      attn, bto, b_out, query, out, M);
}

// Round 4
// 174.981 us; speedup vs baseline: 1.4074x; 1.0624x over previous
//
#include <hip/hip_runtime.h>
#include <type_traits>

#define H_IMG 128
#define W_IMG 128
#define NQ (H_IMG * W_IMG)
#define CIN 256
#define NH 8
#define NP 4
#define DH 32
#define LDSP 264  // padded LDS row stride (bf16 elems) = 33 x 16B slots; (row+q)&7 quad spread

typedef __bf16 bf16x4 __attribute__((ext_vector_type(4)));
typedef __bf16 bf16x8 __attribute__((ext_vector_type(8)));
typedef float f32x4 __attribute__((ext_vector_type(4)));

// ---------------- weight prep: transpose to BT[N][K] and cast to bf16 ----------------
__global__ __launch_bounds__(256) void prep_weights(
    const float* __restrict__ Wval, const float* __restrict__ Wout,
    const float* __restrict__ Woff, const float* __restrict__ Wattn,
    const float* __restrict__ boff, const float* __restrict__ battn,
    __bf16* __restrict__ btv, __bf16* __restrict__ bto,
    __bf16* __restrict__ btoa, float* __restrict__ bias96) {
  int id = blockIdx.x * 256 + threadIdx.x;
  if (id < 256 * 256) {
    int n = id >> 8, k = id & 255;
    btv[n * 256 + k] = (__bf16)Wval[k * 256 + n];
    bto[n * 256 + k] = (__bf16)Wout[k * 256 + n];
  }
  if (id < 96 * 256) {
    int n = id >> 8, k = id & 255;
    float w = (n < 64) ? Woff[k * 64 + n] : Wattn[k * 32 + (n - 64)];
    btoa[n * 256 + k] = (__bf16)w;
  }
  if (id < 96) {
    bias96[id] = (id < 64) ? boff[id] : battn[id - 64];
  }
}

// ---------------- full-K staged 64x64 MFMA GEMM ------------------------------------
// C[M x 256] = A[M x 256] * BT^T + bias (+ addm). One staging phase (A 64x256 ->
// bf16 LDS, B 64x256 bf16 LDS), ONE barrier, then 8 unrolled k-steps of pure
// ds_read+MFMA (no further barriers -> scheduler pipelines freely).
// Staging is linear global->LDS: inst i, thread t covers consecutive 16B chunks;
// LDS rows padded to 264 elems so both stores and frag reads spread all 8 bank-quads.
// mfma_f32_16x16x32_bf16 layouts (HW-verified, carried from passing rounds):
//   A frag: lane holds A[m = lane&15][k = (lane>>4)*8 + j]
//   B frag: lane holds BT[n = lane&15][k = (lane>>4)*8 + j]
//   C/D:    col = lane&15, row = (lane>>4)*4 + reg
template <typename TA, typename TC, bool PLANAR, bool ADD>
__global__ __launch_bounds__(256) void gemm64(
    const TA* __restrict__ A, const __bf16* __restrict__ BT,
    const float* __restrict__ bias, const float* __restrict__ addm,
    TC* __restrict__ C, int M) {
  const int t = threadIdx.x;
  const int lane = t & 63;
  const int wave = t >> 6;
  const int r = lane & 15;
  const int q = lane >> 4;
  const int gm0 = blockIdx.x * 64;
  const int gn0 = blockIdx.y * 64;
  const int wm = (wave & 1) * 32;
  const int wn = (wave >> 1) * 32;

  __shared__ __bf16 As[64 * LDSP];
  __shared__ __bf16 Bs[64 * LDSP];

  // ---- stage A (64 x 256 -> bf16) ----
  if constexpr (std::is_same<TA, float>::value) {
#pragma unroll
    for (int i = 0; i < 16; ++i) {
      int g = i * 256 + t;  // granule = 4 floats
      int row = g >> 6, c4 = g & 63;
      float4 f = *(const float4*)(A + (size_t)(gm0 + row) * 256 + c4 * 4);
      bf16x4 hh;
      hh[0] = (__bf16)f.x; hh[1] = (__bf16)f.y;
      hh[2] = (__bf16)f.z; hh[3] = (__bf16)f.w;
      *(bf16x4*)(&As[row * LDSP + c4 * 4]) = hh;
    }
  } else {
#pragma unroll
    for (int i = 0; i < 8; ++i) {
      int g = i * 256 + t;  // granule = 16 B
      int row = g >> 5, c = g & 31;
      *(bf16x8*)(&As[row * LDSP + c * 8]) =
          *(const bf16x8*)(A + (size_t)(gm0 + row) * 256 + c * 8);
    }
  }
  // ---- stage B (64 x 256 bf16) ----
#pragma unroll
  for (int i = 0; i < 8; ++i) {
    int g = i * 256 + t;
    int row = g >> 5, c = g & 31;
    *(bf16x8*)(&Bs[row * LDSP + c * 8]) =
        *(const bf16x8*)(BT + (size_t)(gn0 + row) * 256 + c * 8);
  }
  __syncthreads();

  f32x4 acc[2][2];
#pragma unroll
  for (int mt = 0; mt < 2; ++mt)
#pragma unroll
    for (int nt = 0; nt < 2; ++nt) acc[mt][nt] = (f32x4){0.f, 0.f, 0.f, 0.f};

#pragma unroll
  for (int kt = 0; kt < 8; ++kt) {
    const int ko = kt * 32 + q * 8;
    bf16x8 a0 = *(const bf16x8*)(&As[(wm + r) * LDSP + ko]);
    bf16x8 a1 = *(const bf16x8*)(&As[(wm + 16 + r) * LDSP + ko]);
    bf16x8 b0 = *(const bf16x8*)(&Bs[(wn + r) * LDSP + ko]);
    bf16x8 b1 = *(const bf16x8*)(&Bs[(wn + 16 + r) * LDSP + ko]);
    acc[0][0] = __builtin_amdgcn_mfma_f32_16x16x32_bf16(a0, b0, acc[0][0], 0, 0, 0);
    acc[0][1] = __builtin_amdgcn_mfma_f32_16x16x32_bf16(a0, b1, acc[0][1], 0, 0, 0);
    acc[1][0] = __builtin_amdgcn_mfma_f32_16x16x32_bf16(a1, b0, acc[1][0], 0, 0, 0);
    acc[1][1] = __builtin_amdgcn_mfma_f32_16x16x32_bf16(a1, b1, acc[1][1], 0, 0, 0);
  }

#pragma unroll
  for (int mt = 0; mt < 2; ++mt)
#pragma unroll
    for (int nt = 0; nt < 2; ++nt)
#pragma unroll
      for (int rr = 0; rr < 4; ++rr) {
        int row = gm0 + wm + mt * 16 + q * 4 + rr;
        int col = gn0 + wn + nt * 16 + r;
        float val = acc[mt][nt][rr] + bias[col];
        if constexpr (ADD) val += addm[(size_t)row * 256 + col];
        if constexpr (PLANAR)
          C[((size_t)(col >> 5) * M + row) * 32 + (col & 31)] = (TC)val;
        else
          C[(size_t)row * 256 + col] = (TC)val;
      }
}

// ---------------- fused offsets/logits GEMM + sampling -----------------------------
// Block = 64 queries. Phase A: oa[64x96] = query_tile @ btoa^T + bias96, A full-K
// staged in LDS, B direct from global (btoa = 48 KB, L1/L2 hot), result to LDS.
// Phase B: softmax over P=4 + bilinear gathers from head-planar v, write attn bf16.
// Kills the 24 MB oa HBM round trip of the unfused version.
__global__ __launch_bounds__(256) void oa_sample(
    const float* __restrict__ query, const __bf16* __restrict__ btoa,
    const float* __restrict__ bias96, const __bf16* __restrict__ v,
    __bf16* __restrict__ attn, int M) {
  const int t = threadIdx.x;
  const int lane = t & 63;
  const int wave = t >> 6;
  const int r = lane & 15;
  const int q = lane >> 4;
  const int gm0 = blockIdx.x * 64;
  const int wm = (wave & 1) * 32;
  const int n0 = (wave >> 1) * 48;

  __shared__ __bf16 As[64 * LDSP];
  __shared__ float oas[64 * 100];

  // ---- stage query tile (64 x 256 fp32 -> bf16) ----
#pragma unroll
  for (int i = 0; i < 16; ++i) {
    int g = i * 256 + t;
    int row = g >> 6, c4 = g & 63;
    float4 f = *(const float4*)(query + (size_t)(gm0 + row) * 256 + c4 * 4);
    bf16x4 hh;
    hh[0] = (__bf16)f.x; hh[1] = (__bf16)f.y;
    hh[2] = (__bf16)f.z; hh[3] = (__bf16)f.w;
    *(bf16x4*)(&As[row * LDSP + c4 * 4]) = hh;
  }
  __syncthreads();

  f32x4 acc[2][3];
#pragma unroll
  for (int mt = 0; mt < 2; ++mt)
#pragma unroll
    for (int nt = 0; nt < 3; ++nt) acc[mt][nt] = (f32x4){0.f, 0.f, 0.f, 0.f};

#pragma unroll
  for (int kt = 0; kt < 8; ++kt) {
    const int ko = kt * 32 + q * 8;
    bf16x8 a0 = *(const bf16x8*)(&As[(wm + r) * LDSP + ko]);
    bf16x8 a1 = *(const bf16x8*)(&As[(wm + 16 + r) * LDSP + ko]);
    bf16x8 b[3];
#pragma unroll
    for (int nt = 0; nt < 3; ++nt)
      b[nt] = *(const bf16x8*)(btoa + (size_t)(n0 + nt * 16 + r) * 256 + ko);
#pragma unroll
    for (int nt = 0; nt < 3; ++nt) {
      acc[0][nt] = __builtin_amdgcn_mfma_f32_16x16x32_bf16(a0, b[nt], acc[0][nt], 0, 0, 0);
      acc[1][nt] = __builtin_amdgcn_mfma_f32_16x16x32_bf16(a1, b[nt], acc[1][nt], 0, 0, 0);
    }
  }
#pragma unroll
  for (int mt = 0; mt < 2; ++mt)
#pragma unroll
    for (int nt = 0; nt < 3; ++nt)
#pragma unroll
      for (int rr = 0; rr < 4; ++rr) {
        int rl = wm + mt * 16 + q * 4 + rr;
        int col = n0 + nt * 16 + r;
        oas[rl * 100 + col] = acc[mt][nt][rr] + bias96[col];
      }
  __syncthreads();

  // ---- phase B: sample this block's 64 queries ----
  const int qrow = t >> 2;
  const int c8 = (t & 3) * 8;
  const int row = gm0 + qrow;
  const int b = row >> 14;  // nq = 16384
  const int qi = row & (NQ - 1);
  const int x = qi & (W_IMG - 1);
  const int y = qi >> 7;
  const float* oar = &oas[qrow * 100];
#pragma unroll
  for (int h = 0; h < NH; ++h) {
    float l0 = oar[64 + h * 4 + 0];
    float l1 = oar[64 + h * 4 + 1];
    float l2 = oar[64 + h * 4 + 2];
    float l3 = oar[64 + h * 4 + 3];
    float mx = fmaxf(fmaxf(l0, l1), fmaxf(l2, l3));
    float e0 = __expf(l0 - mx), e1 = __expf(l1 - mx);
    float e2 = __expf(l2 - mx), e3 = __expf(l3 - mx);
    float inv = 1.f / (e0 + e1 + e2 + e3);
    float awp[4] = {e0 * inv, e1 * inv, e2 * inv, e3 * inv};
    float fa[8] = {0.f, 0.f, 0.f, 0.f, 0.f, 0.f, 0.f, 0.f};
    const __bf16* vh = v + ((size_t)h * M + (size_t)b * NQ) * 32 + c8;
#pragma unroll
    for (int p = 0; p < NP; ++p) {
      float ox = oar[h * 8 + p * 2 + 0];
      float oy = oar[h * 8 + p * 2 + 1];
      float ix = (float)x + ox;
      float iy = (float)y + oy;
      float x0f = floorf(ix), y0f = floorf(iy);
      float wx1 = ix - x0f, wy1 = iy - y0f;
      int x0 = (int)x0f, y0 = (int)y0f;
      float wgt[4] = {(1.f - wx1) * (1.f - wy1), wx1 * (1.f - wy1),
                      (1.f - wx1) * wy1, wx1 * wy1};
      int xs[4] = {x0, x0 + 1, x0, x0 + 1};
      int ysv[4] = {y0, y0, y0 + 1, y0 + 1};
#pragma unroll
      for (int c = 0; c < 4; ++c) {
        int xi = xs[c], yi = ysv[c];
        bool valid = (xi >= 0) & (xi < W_IMG) & (yi >= 0) & (yi < H_IMG);
        int xc = xi < 0 ? 0 : (xi > W_IMG - 1 ? W_IMG - 1 : xi);
        int yc = yi < 0 ? 0 : (yi > H_IMG - 1 ? H_IMG - 1 : yi);
        float wv = awp[p] * wgt[c] * (valid ? 1.f : 0.f);
        bf16x8 g = *(const bf16x8*)(vh + (size_t)(yc * W_IMG + xc) * 32);
#pragma unroll
        for (int j = 0; j < 8; ++j) fa[j] += wv * (float)g[j];
      }
    }
    bf16x8 o;
#pragma unroll
    for (int j = 0; j < 8; ++j) o[j] = (__bf16)fa[j];
    *(bf16x8*)(attn + (size_t)row * 256 + h * DH + c8) = o;
  }
}

extern "C" void kernel_launch(void* const* d_in, const int* in_sizes, int n_in,
                              void* d_out, int out_size, void* d_ws, size_t ws_size,
                              hipStream_t stream) {
  const float* query  = (const float*)d_in[0];
  const float* value  = (const float*)d_in[1];
  const float* W_off  = (const float*)d_in[2];
  const float* b_off  = (const float*)d_in[3];
  const float* W_attn = (const float*)d_in[4];
  const float* b_attn = (const float*)d_in[5];
  const float* W_val  = (const float*)d_in[6];
  const float* b_val  = (const float*)d_in[7];
  const float* W_out  = (const float*)d_in[8];
  const float* b_out  = (const float*)d_in[9];
  float* out = (float*)d_out;

  char* ws = (char*)d_ws;
  __bf16* btv    = (__bf16*)(ws + 0);          // 128 KB
  __bf16* bto    = (__bf16*)(ws + 131072);     // 128 KB
  __bf16* btoa   = (__bf16*)(ws + 262144);     // 48 KB
  float*  bias96 = (float*)(ws + 311296);      // 384 B
  __bf16* v      = (__bf16*)(ws + 524288);     // 16 MB (bf16, head-planar)
  __bf16* attn   = (__bf16*)(ws + 17301504);   // 16 MB (bf16)

  const int M = in_sizes[0] / CIN;  // 32768 = bs * nq

  prep_weights<<<256, 256, 0, stream>>>(W_val, W_out, W_off, W_attn,
                                        b_off, b_attn, btv, bto, btoa, bias96);
  // v = value @ W_val + b_val  (bf16, head-planar)
  gemm64<float, __bf16, true, false><<<dim3(M / 64, 4), 256, 0, stream>>>(
      value, btv, b_val, nullptr, v, M);
  // oa GEMM + deformable sampling fused
  oa_sample<<<M / 64, 256, 0, stream>>>(query, btoa, bias96, v, attn, M);
  // out = attn @ W_out + b_out + query  (fp32)
  gemm64<__bf16, float, false, true><<<dim3(M / 64, 4), 256, 0, stream>>>(
      attn, bto, b_out, query, out, M);
}

// Round 5
// 167.557 us; speedup vs baseline: 1.4697x; 1.0443x over previous
//
#include <hip/hip_runtime.h>

#define H_IMG 128
#define W_IMG 128
#define NQ (H_IMG * W_IMG)
#define CIN 256
#define NH 8
#define NP 4
#define DH 32
#define LDSP 264  // padded LDS row stride (bf16 elems); 264%32=8 -> 2-way max aliasing (free)

typedef __bf16 bf16x4 __attribute__((ext_vector_type(4)));
typedef __bf16 bf16x8 __attribute__((ext_vector_type(8)));
typedef float f32x4 __attribute__((ext_vector_type(4)));

// ---------------- weight prep: transpose to BT[N][K] and cast to bf16 ----------------
__global__ __launch_bounds__(256) void prep_weights(
    const float* __restrict__ Wval, const float* __restrict__ Wout,
    const float* __restrict__ Woff, const float* __restrict__ Wattn,
    const float* __restrict__ boff, const float* __restrict__ battn,
    __bf16* __restrict__ btv, __bf16* __restrict__ bto,
    __bf16* __restrict__ btoa, float* __restrict__ bias96) {
  int id = blockIdx.x * 256 + threadIdx.x;
  if (id < 256 * 256) {
    int n = id >> 8, k = id & 255;
    btv[n * 256 + k] = (__bf16)Wval[k * 256 + n];
    bto[n * 256 + k] = (__bf16)Wout[k * 256 + n];
  }
  if (id < 96 * 256) {
    int n = id >> 8, k = id & 255;
    float w = (n < 64) ? Woff[k * 64 + n] : Wattn[k * 32 + (n - 64)];
    btoa[n * 256 + k] = (__bf16)w;
  }
  if (id < 96) {
    bias96[id] = (id < 64) ? boff[id] : battn[id - 64];
  }
}

// ---------------- K1: v = value @ W_val + b_val (head-planar bf16 out) -------------
// Block = 64 rows x FULL N=256 (A read exactly once). 4 waves; wave w covers all 64
// rows (4 m-tiles) x cols [w*64, w*64+64) (4 n-tiles) => 16 accs, 128 MFMA/wave.
// A staged full-K in LDS (one barrier); B-frags streamed from global btv (128 KB,
// L2-hot, reused by all 512 blocks).
// mfma_f32_16x16x32_bf16 layouts (HW-verified, carried from passing rounds):
//   A frag: lane holds A[m = lane&15][k = (lane>>4)*8 + j]
//   B frag: lane holds BT[n = lane&15][k = (lane>>4)*8 + j]
//   C/D:    col = lane&15, row = (lane>>4)*4 + reg
__global__ __launch_bounds__(256) void gemm_v(
    const float* __restrict__ A, const __bf16* __restrict__ BT,
    const float* __restrict__ bias, __bf16* __restrict__ v, int M) {
  const int t = threadIdx.x;
  const int lane = t & 63;
  const int wave = t >> 6;
  const int r = lane & 15;
  const int q = lane >> 4;
  const int gm0 = blockIdx.x * 64;
  const int wn = wave * 64;

  __shared__ __bf16 As[64 * LDSP];

  // stage A (64 x 256 fp32 -> bf16), coalesced, conflict-free
#pragma unroll
  for (int i = 0; i < 16; ++i) {
    int g = i * 256 + t;
    int row = g >> 6, c4 = g & 63;
    float4 f = *(const float4*)(A + (size_t)(gm0 + row) * 256 + c4 * 4);
    bf16x4 hh;
    hh[0] = (__bf16)f.x; hh[1] = (__bf16)f.y;
    hh[2] = (__bf16)f.z; hh[3] = (__bf16)f.w;
    *(bf16x4*)(&As[row * LDSP + c4 * 4]) = hh;
  }
  __syncthreads();

  f32x4 acc[4][4];
#pragma unroll
  for (int mt = 0; mt < 4; ++mt)
#pragma unroll
    for (int nt = 0; nt < 4; ++nt) acc[mt][nt] = (f32x4){0.f, 0.f, 0.f, 0.f};

#pragma unroll
  for (int kt = 0; kt < 8; ++kt) {
    const int ko = kt * 32 + q * 8;
    bf16x8 a[4], b[4];
#pragma unroll
    for (int mt = 0; mt < 4; ++mt)
      a[mt] = *(const bf16x8*)(&As[(mt * 16 + r) * LDSP + ko]);
#pragma unroll
    for (int nt = 0; nt < 4; ++nt)
      b[nt] = *(const bf16x8*)(BT + (size_t)(wn + nt * 16 + r) * 256 + ko);
#pragma unroll
    for (int mt = 0; mt < 4; ++mt)
#pragma unroll
      for (int nt = 0; nt < 4; ++nt)
        acc[mt][nt] =
            __builtin_amdgcn_mfma_f32_16x16x32_bf16(a[mt], b[nt], acc[mt][nt], 0, 0, 0);
  }

  // epilogue: head-planar scatter v[head][row][col&31]
#pragma unroll
  for (int mt = 0; mt < 4; ++mt)
#pragma unroll
    for (int nt = 0; nt < 4; ++nt)
#pragma unroll
      for (int rr = 0; rr < 4; ++rr) {
        int row = gm0 + mt * 16 + q * 4 + rr;
        int col = wn + nt * 16 + r;
        v[((size_t)(col >> 5) * M + row) * 32 + (col & 31)] =
            (__bf16)(acc[mt][nt][rr] + bias[col]);
      }
}

// ---------------- K2: oa GEMM + sampling + output GEMM, fully fused ----------------
// Block = 64 queries. Phases (LDS reused):
//  1. stage query tile -> bf16 As (one barrier)
//  2. oa[64x96] = q @ btoa^T + bias96 -> oas LDS   (B from L2-hot global)
//  3. softmax + bilinear sampling from head-planar v -> attn tile WRITTEN INTO As
//     (As is dead: the pre-phase barrier drained all its ds_reads)
//  4. out = attn(LDS) @ bto^T + b_out + query(L2 re-read of own tile) -> global
// Kills the 16 MB attn write + 64 MB re-read of the unfused pipeline.
__global__ __launch_bounds__(256) void oa_sample_out(
    const float* __restrict__ query, const __bf16* __restrict__ btoa,
    const float* __restrict__ bias96, const __bf16* __restrict__ v,
    const __bf16* __restrict__ bto, const float* __restrict__ b_out,
    float* __restrict__ out, int M) {
  const int t = threadIdx.x;
  const int lane = t & 63;
  const int wave = t >> 6;
  const int r = lane & 15;
  const int q = lane >> 4;
  const int gm0 = blockIdx.x * 64;

  __shared__ __bf16 As[64 * LDSP];
  __shared__ float oas[64 * 100];

  // ---- phase 1: stage query (64 x 256 fp32 -> bf16) ----
#pragma unroll
  for (int i = 0; i < 16; ++i) {
    int g = i * 256 + t;
    int row = g >> 6, c4 = g & 63;
    float4 f = *(const float4*)(query + (size_t)(gm0 + row) * 256 + c4 * 4);
    bf16x4 hh;
    hh[0] = (__bf16)f.x; hh[1] = (__bf16)f.y;
    hh[2] = (__bf16)f.z; hh[3] = (__bf16)f.w;
    *(bf16x4*)(&As[row * LDSP + c4 * 4]) = hh;
  }
  __syncthreads();

  // ---- phase 2: oa GEMM (wave: 2 m-tiles x 3 n-tiles) ----
  {
    const int wm = (wave & 1) * 32;
    const int n0 = (wave >> 1) * 48;
    f32x4 acc[2][3];
#pragma unroll
    for (int mt = 0; mt < 2; ++mt)
#pragma unroll
      for (int nt = 0; nt < 3; ++nt) acc[mt][nt] = (f32x4){0.f, 0.f, 0.f, 0.f};
#pragma unroll
    for (int kt = 0; kt < 8; ++kt) {
      const int ko = kt * 32 + q * 8;
      bf16x8 a0 = *(const bf16x8*)(&As[(wm + r) * LDSP + ko]);
      bf16x8 a1 = *(const bf16x8*)(&As[(wm + 16 + r) * LDSP + ko]);
      bf16x8 b[3];
#pragma unroll
      for (int nt = 0; nt < 3; ++nt)
        b[nt] = *(const bf16x8*)(btoa + (size_t)(n0 + nt * 16 + r) * 256 + ko);
#pragma unroll
      for (int nt = 0; nt < 3; ++nt) {
        acc[0][nt] = __builtin_amdgcn_mfma_f32_16x16x32_bf16(a0, b[nt], acc[0][nt], 0, 0, 0);
        acc[1][nt] = __builtin_amdgcn_mfma_f32_16x16x32_bf16(a1, b[nt], acc[1][nt], 0, 0, 0);
      }
    }
#pragma unroll
    for (int mt = 0; mt < 2; ++mt)
#pragma unroll
      for (int nt = 0; nt < 3; ++nt)
#pragma unroll
        for (int rr = 0; rr < 4; ++rr) {
          int rl = wm + mt * 16 + q * 4 + rr;
          int col = n0 + nt * 16 + r;
          oas[rl * 100 + col] = acc[mt][nt][rr] + bias96[col];
        }
  }
  __syncthreads();  // oas ready; all As reads drained -> As reusable

  // ---- phase 3: sample 64 queries, write attn tile into As ----
  {
    const int qrow = t >> 2;
    const int c8 = (t & 3) * 8;
    const int row = gm0 + qrow;
    const int b = row >> 14;  // nq = 16384
    const int qi = row & (NQ - 1);
    const int x = qi & (W_IMG - 1);
    const int y = qi >> 7;
    const float* oar = &oas[qrow * 100];
#pragma unroll
    for (int h = 0; h < NH; ++h) {
      float l0 = oar[64 + h * 4 + 0];
      float l1 = oar[64 + h * 4 + 1];
      float l2 = oar[64 + h * 4 + 2];
      float l3 = oar[64 + h * 4 + 3];
      float mx = fmaxf(fmaxf(l0, l1), fmaxf(l2, l3));
      float e0 = __expf(l0 - mx), e1 = __expf(l1 - mx);
      float e2 = __expf(l2 - mx), e3 = __expf(l3 - mx);
      float inv = 1.f / (e0 + e1 + e2 + e3);
      float awp[4] = {e0 * inv, e1 * inv, e2 * inv, e3 * inv};
      float fa[8] = {0.f, 0.f, 0.f, 0.f, 0.f, 0.f, 0.f, 0.f};
      const __bf16* vh = v + ((size_t)h * M + (size_t)b * NQ) * 32 + c8;
#pragma unroll
      for (int p = 0; p < NP; ++p) {
        float ox = oar[h * 8 + p * 2 + 0];
        float oy = oar[h * 8 + p * 2 + 1];
        float ix = (float)x + ox;
        float iy = (float)y + oy;
        float x0f = floorf(ix), y0f = floorf(iy);
        float wx1 = ix - x0f, wy1 = iy - y0f;
        int x0 = (int)x0f, y0 = (int)y0f;
        float wgt[4] = {(1.f - wx1) * (1.f - wy1), wx1 * (1.f - wy1),
                        (1.f - wx1) * wy1, wx1 * wy1};
        int xs[4] = {x0, x0 + 1, x0, x0 + 1};
        int ysv[4] = {y0, y0, y0 + 1, y0 + 1};
#pragma unroll
        for (int c = 0; c < 4; ++c) {
          int xi = xs[c], yi = ysv[c];
          bool valid = (xi >= 0) & (xi < W_IMG) & (yi >= 0) & (yi < H_IMG);
          int xc = xi < 0 ? 0 : (xi > W_IMG - 1 ? W_IMG - 1 : xi);
          int yc = yi < 0 ? 0 : (yi > H_IMG - 1 ? H_IMG - 1 : yi);
          float wv = awp[p] * wgt[c] * (valid ? 1.f : 0.f);
          bf16x8 g = *(const bf16x8*)(vh + (size_t)(yc * W_IMG + xc) * 32);
#pragma unroll
          for (int j = 0; j < 8; ++j) fa[j] += wv * (float)g[j];
        }
      }
      bf16x8 o;
#pragma unroll
      for (int j = 0; j < 8; ++j) o[j] = (__bf16)fa[j];
      *(bf16x8*)(&As[qrow * LDSP + h * DH + c8]) = o;
    }
  }
  __syncthreads();  // attn tile ready in As

  // ---- phase 4: out GEMM (wave: all 64 rows x 64 cols = 4x4 tiles) ----
  {
    const int wn = wave * 64;
    f32x4 acc[4][4];
#pragma unroll
    for (int mt = 0; mt < 4; ++mt)
#pragma unroll
      for (int nt = 0; nt < 4; ++nt) acc[mt][nt] = (f32x4){0.f, 0.f, 0.f, 0.f};
#pragma unroll
    for (int kt = 0; kt < 8; ++kt) {
      const int ko = kt * 32 + q * 8;
      bf16x8 a[4], b[4];
#pragma unroll
      for (int mt = 0; mt < 4; ++mt)
        a[mt] = *(const bf16x8*)(&As[(mt * 16 + r) * LDSP + ko]);
#pragma unroll
      for (int nt = 0; nt < 4; ++nt)
        b[nt] = *(const bf16x8*)(bto + (size_t)(wn + nt * 16 + r) * 256 + ko);
#pragma unroll
      for (int mt = 0; mt < 4; ++mt)
#pragma unroll
        for (int nt = 0; nt < 4; ++nt)
          acc[mt][nt] =
              __builtin_amdgcn_mfma_f32_16x16x32_bf16(a[mt], b[nt], acc[mt][nt], 0, 0, 0);
    }
#pragma unroll
    for (int mt = 0; mt < 4; ++mt)
#pragma unroll
      for (int nt = 0; nt < 4; ++nt)
#pragma unroll
        for (int rr = 0; rr < 4; ++rr) {
          int row = gm0 + mt * 16 + q * 4 + rr;
          int col = wn + nt * 16 + r;
          out[(size_t)row * 256 + col] =
              acc[mt][nt][rr] + b_out[col] + query[(size_t)row * 256 + col];
        }
  }
}

extern "C" void kernel_launch(void* const* d_in, const int* in_sizes, int n_in,
                              void* d_out, int out_size, void* d_ws, size_t ws_size,
                              hipStream_t stream) {
  const float* query  = (const float*)d_in[0];
  const float* value  = (const float*)d_in[1];
  const float* W_off  = (const float*)d_in[2];
  const float* b_off  = (const float*)d_in[3];
  const float* W_attn = (const float*)d_in[4];
  const float* b_attn = (const float*)d_in[5];
  const float* W_val  = (const float*)d_in[6];
  const float* b_val  = (const float*)d_in[7];
  const float* W_out  = (const float*)d_in[8];
  const float* b_out  = (const float*)d_in[9];
  float* out = (float*)d_out;

  char* ws = (char*)d_ws;
  __bf16* btv    = (__bf16*)(ws + 0);          // 128 KB
  __bf16* bto    = (__bf16*)(ws + 131072);     // 128 KB
  __bf16* btoa   = (__bf16*)(ws + 262144);     // 48 KB
  float*  bias96 = (float*)(ws + 311296);      // 384 B
  __bf16* v      = (__bf16*)(ws + 524288);     // 16 MB (bf16, head-planar)

  const int M = in_sizes[0] / CIN;  // 32768 = bs * nq

  prep_weights<<<256, 256, 0, stream>>>(W_val, W_out, W_off, W_attn,
                                        b_off, b_attn, btv, bto, btoa, bias96);
  gemm_v<<<M / 64, 256, 0, stream>>>(value, btv, b_val, v, M);
  oa_sample_out<<<M / 64, 256, 0, stream>>>(query, btoa, bias96, v, bto, b_out, out, M);
}